// Round 1
// 100.523 us; speedup vs baseline: 1.0321x; 1.0321x over previous
//
#include <hip/hip_runtime.h>

typedef unsigned short ushort;
typedef unsigned int uint;
typedef unsigned char uchar;
typedef __attribute__((ext_vector_type(8))) int intx8;
typedef __attribute__((ext_vector_type(16))) float floatx16;

// Problem constants
#define T_STEPS 100
#define BATCH   32
#define NIN     1024
#define NOUT    512

// K layout: k = b*SEG + t, t padded 100 -> 128 (multiple of 64 so the
// MX-scaled 32x32x64 MFMA tiles K exactly). Operands stored fp8 e4m3,
// [rows][K], row stride 4160 B = 16.25 x 256B (rotates L2 channels).
#define SEG      128
#define KPAD     (BATCH * SEG)         // 4096 (GEMM K extent, bytes = elems)
#define KSTRIDEB 4160                  // row stride in bytes
#define KS       16
#define KCHUNK   (KPAD / KS)           // 256 -> 4 K-steps of 64 per block

#define LR_LTP  (1e-4f)
#define LR_LTD  (-1e-4f)
#define INV_B   (1.0f / 32.0f)
#define DECAY   0.951229424500714f     // exp(-1/20)
#define D32     0.201896517994655f     // exp(-32/20)
#define TCH     32                     // t-chunk per thread
#define NCHUNK  4

// Output layout (floats): [delta_w | pre_tr_final | post_tr_final]
#define OFF_PRE  (NOUT * NIN)
#define OFF_POST (OFF_PRE + BATCH * NIN)

// Workspace (bytes): 4 fp8 operands, then bf16 Spart slabs
#define B_PRST  0
#define B_PRTT  ((size_t)NIN * KSTRIDEB)
#define B_POST  ((size_t)2 * NIN * KSTRIDEB)
#define B_POTT  ((size_t)2 * NIN * KSTRIDEB + (size_t)NOUT * KSTRIDEB)
#define B_END   ((size_t)2 * (NIN + NOUT) * KSTRIDEB)   // 12,779,520 B (16-aligned)
// bf16 partial slab stride: NOUT*NIN + 128 ushorts = 1,048,832 B = 4097 x 256B
// (odd 256B multiple -> full L2 channel rotation across slabs)
#define SLABU   (NOUT * NIN + 128)

// NOTE (hard-won, prior session rounds 8+10): no device-scope atomics storms
// and no __threadfence-based cross-block reduction inside the hot kernels —
// both serialized the whole GPU (5-10x regressions). The 3-dispatch structure
// with streamed bf16 partial slabs is the proven optimum here.
//
// NOTE (this round): kernel B dropped LDS staging + barriers entirely. The
// MX 32x32x64 f8f6f4 fragment is "row = lane&31, 32 contiguous K bytes at
// (lane>>5)*32" — identical to our [row][K] operand layout, so lanes load
// fragments straight from global (L2-resident) and the K-loop has zero
// __syncthreads / vmcnt(0) drains.

static __device__ __forceinline__ uint pk4_fp8(float a, float b, float c, float d) {
    uint v = 0;
    v = __builtin_amdgcn_cvt_pk_fp8_f32(a, b, v, false);   // low 16 bits
    v = __builtin_amdgcn_cvt_pk_fp8_f32(c, d, v, true);    // high 16 bits
    return v;
}

static __device__ __forceinline__ ushort f2bf(float f) {
    union { float f; unsigned int u; } v; v.f = f;
    unsigned int r = (v.u + 0x7FFFu + ((v.u >> 16) & 1u)) >> 16;   // RNE
    return (ushort)r;
}

// ---------------------------------------------------------------------------
// Kernel A: trace recurrence fused with transpose, fp8 e4m3 outputs.
// Block = 64 chains x 4 t-chunks of 32 (t >= 100: spikes zero-padded).
// Split scan with exp(-32/20) carry fixup. fp8-packed results staged in LDS
// rows of 33 words, then written out cooperatively as 16B chunks.
// ---------------------------------------------------------------------------
__global__ __launch_bounds__(256) void stdp_traces_t(
    const float* __restrict__ pre_s,    // [T,B,NIN]
    const float* __restrict__ post_s,   // [T,B,NOUT]
    const float* __restrict__ pre_tr0,  // [B,NIN]
    const float* __restrict__ post_tr0, // [B,NOUT]
    uchar* __restrict__ pre_s_t, uchar* __restrict__ pre_tr_t,
    uchar* __restrict__ post_s_t, uchar* __restrict__ post_tr_t,
    float* __restrict__ out)
{
    __shared__ uint Ls[64 * 33];   // packed fp8 spikes, 8.25 KB
    __shared__ uint Lt[64 * 33];   // packed fp8 traces
    __shared__ float Eend[NCHUNK][64];

    const int chain = threadIdx.x & 63;
    const int c     = threadIdx.x >> 6;     // t-chunk, wave-uniform
    const int g     = blockIdx.x * 64 + chain;

    const float* src; const float* init;
    int id, stride, outoff;
    if (g < BATCH * NIN) {
        src = pre_s;  init = pre_tr0;
        id = g;               stride = BATCH * NIN;  outoff = OFF_PRE;
    } else {
        src = post_s; init = post_tr0;
        id = g - BATCH * NIN; stride = BATCH * NOUT; outoff = OFF_POST;
    }

    const int t0 = c * TCH;
    float x[TCH];
    #pragma unroll
    for (int m = 0; m < TCH; ++m)
        x[m] = (t0 + m < T_STEPS) ? src[(size_t)(t0 + m) * stride + id] : 0.f;

    // pack spikes to fp8 before the scan overwrites x[]
    uint sp[8];
    #pragma unroll
    for (int j = 0; j < 8; ++j)
        sp[j] = pk4_fp8(x[4*j], x[4*j+1], x[4*j+2], x[4*j+3]);

    // local scan (zero initial condition)
    float e = 0.f;
    #pragma unroll
    for (int m = 0; m < TCH; ++m) { e = e * DECAY + x[m]; x[m] = e; }
    Eend[c][chain] = e;
    __syncthreads();

    // carry into chunk c
    float C = init[id];
    for (int cc = 0; cc < c; ++cc) C = C * D32 + Eend[cc][chain];
    float p = C * DECAY;
    #pragma unroll
    for (int m = 0; m < TCH; ++m) { x[m] += p; p *= DECAY; }

    if (c == NCHUNK - 1) out[outoff + id] = x[3];   // t = 96 + 3 = 99

    // stage packed fp8 into LDS (trace values for t>=100 are decayed garbage
    // but are always multiplied by zero-padded spikes in the GEMM)
    #pragma unroll
    for (int j = 0; j < 8; ++j) {
        const uint tj = pk4_fp8(x[4*j], x[4*j+1], x[4*j+2], x[4*j+3]);
        Ls[chain * 33 + c * 8 + j] = sp[j];
        Lt[chain * 33 + c * 8 + j] = tj;
    }
    __syncthreads();

    // cooperative coalesced write-out: 2 ops x 64 rows x 8 16B-chunks = 1024
    const int id0 = blockIdx.x * 64;
    uchar *dS, *dT; int b0, ch0;
    if (id0 < BATCH * NIN) {
        b0 = id0 >> 10; ch0 = id0 & 1023; dS = pre_s_t;  dT = pre_tr_t;
    } else {
        const int idq = id0 - BATCH * NIN;
        b0 = idq >> 9;  ch0 = idq & 511;  dS = post_s_t; dT = post_tr_t;
    }
    #pragma unroll
    for (int j = 0; j < 4; ++j) {
        const int q  = threadIdx.x + 256 * j;   // 0..1023, all valid
        const int op = q >> 9;
        const int qq = q & 511;
        const int r  = qq >> 3;
        const int cc = qq & 7;
        const uint* l = (op ? Lt : Ls) + r * 33 + cc * 4;
        const uint4 v = make_uint4(l[0], l[1], l[2], l[3]);
        uchar* gd = (op ? dT : dS) + (size_t)(ch0 + r) * KSTRIDEB + b0 * SEG + cc * 16;
        *(uint4*)gd = v;
    }
}

// ---------------------------------------------------------------------------
// Kernel B: dual MX-fp8 MFMA GEMM (mfma_scale 32x32x64, scale=1.0), 128x128
// tile, 4 waves 2x2, KS=16 K-split (512 blocks = 2/CU, 4 K-steps of 64).
// No LDS, no barriers: fragments loaded per-lane direct from global
// (row = lane&31, 32 contiguous K bytes at (lane>>5)*32 — matches storage).
//   P[o,i] = sum_k post_s[k,o]*pre_tr[k,i]
//   D[o,i] = sum_k post_tr[k,o]*pre_s[k,i]
// Epilogue pre-combines with w and stores BF16 partials:
//   Spart[z][o,i] = bf16( c1*(1-w)*P + c2*w*D )
// Grid (8,4,16) x-fastest: blocks sharing a B-slab (same x) land on one XCD
// under round-robin dispatch -> B rows stay in that L2. Keep.
// ---------------------------------------------------------------------------
static __device__ __forceinline__ intx8 ld32(const uchar* p) {
    const uint4 lo = *(const uint4*)p;
    const uint4 hv = *(const uint4*)(p + 16);
    intx8 r;
    r[0] = (int)lo.x; r[1] = (int)lo.y; r[2] = (int)lo.z; r[3] = (int)lo.w;
    r[4] = (int)hv.x; r[5] = (int)hv.y; r[6] = (int)hv.z; r[7] = (int)hv.w;
    return r;
}

__global__ __launch_bounds__(256, 2) void stdp_gemm_dual(
    const uchar* __restrict__ post_s_t, const uchar* __restrict__ pre_tr_t,
    const uchar* __restrict__ post_tr_t, const uchar* __restrict__ pre_s_t,
    const float* __restrict__ wmat, ushort* __restrict__ Spart)
{
    const int i0 = blockIdx.x * 128;
    const int o0 = blockIdx.y * 128;
    const int k0 = blockIdx.z * KCHUNK;

    const int tid  = threadIdx.x;
    const int w    = tid >> 6;
    const int lane = tid & 63;
    const int wm   = w & 1;
    const int wn   = w >> 1;
    const int l32  = lane & 31;
    const int hi   = lane >> 5;

    floatx16 accP[2][2], accD[2][2];
    #pragma unroll
    for (int mt = 0; mt < 2; ++mt)
        #pragma unroll
        for (int nt = 0; nt < 2; ++nt)
            #pragma unroll
            for (int r = 0; r < 16; ++r) {
                accP[mt][nt][r] = 0.f; accD[mt][nt][r] = 0.f;
            }

    const size_t aBase = (size_t)(o0 + wm * 64 + l32) * KSTRIDEB;
    const size_t bBase = (size_t)(i0 + wn * 64 + l32) * KSTRIDEB;

    for (int kb = k0; kb < k0 + KCHUNK; kb += 64) {
        const int ko = kb + (hi << 5);
        intx8 aP[2], aD[2], bP[2], bD[2];
        #pragma unroll
        for (int mt = 0; mt < 2; ++mt) {
            const size_t off = aBase + (size_t)(mt * 32) * KSTRIDEB + ko;
            aP[mt] = ld32(post_s_t  + off);
            aD[mt] = ld32(post_tr_t + off);
        }
        #pragma unroll
        for (int nt = 0; nt < 2; ++nt) {
            const size_t off = bBase + (size_t)(nt * 32) * KSTRIDEB + ko;
            bP[nt] = ld32(pre_tr_t + off);
            bD[nt] = ld32(pre_s_t  + off);
        }
        #pragma unroll
        for (int mt = 0; mt < 2; ++mt)
            #pragma unroll
            for (int nt = 0; nt < 2; ++nt) {
                accP[mt][nt] = __builtin_amdgcn_mfma_scale_f32_32x32x64_f8f6f4(
                    aP[mt], bP[nt], accP[mt][nt], 0, 0, 0, 127, 0, 127);
                accD[mt][nt] = __builtin_amdgcn_mfma_scale_f32_32x32x64_f8f6f4(
                    aD[mt], bD[nt], accD[mt][nt], 0, 0, 0, 127, 0, 127);
            }
    }

    // epilogue: 32x32 C/D layout col = lane&31 (i), row = (r&3)+8*(r>>2)+4*hi (o)
    ushort* Sz = Spart + (size_t)blockIdx.z * SLABU;
    const float c1 = LR_LTP * INV_B;
    const float c2 = LR_LTD * INV_B;
    #pragma unroll
    for (int mt = 0; mt < 2; ++mt) {
        const int ob = o0 + wm * 64 + mt * 32 + hi * 4;
        #pragma unroll
        for (int nt = 0; nt < 2; ++nt) {
            const int i = i0 + wn * 64 + nt * 32 + l32;
            #pragma unroll
            for (int r = 0; r < 16; ++r) {
                const int o = ob + (r & 3) + 8 * (r >> 2);
                const size_t idx = (size_t)o * NIN + i;
                const float wv = wmat[idx];
                const float v = c1 * (1.0f - wv) * accP[mt][nt][r]
                              + c2 * wv          * accD[mt][nt][r];
                Sz[idx] = f2bf(v);
            }
        }
    }
}

// ---------------------------------------------------------------------------
// Kernel C: sum the KS bf16 slabs -> fp32 dw. One thread per 8 outputs
// (16B slab loads), fp32 accumulation via bit-unpack.
// 512 blocks x 128 threads (2 blocks/CU) to cover the 16-load latency chains.
// ---------------------------------------------------------------------------
__global__ __launch_bounds__(128) void stdp_finalize(
    const ushort* __restrict__ Spart, float* __restrict__ out)
{
    const int j = blockIdx.x * blockDim.x + threadIdx.x;   // 8-element group
    float s[8] = {0.f, 0.f, 0.f, 0.f, 0.f, 0.f, 0.f, 0.f};
    #pragma unroll
    for (int z = 0; z < KS; ++z) {
        const uint4 v = *(const uint4*)(Spart + (size_t)z * SLABU + (size_t)j * 8);
        const uint u[4] = {v.x, v.y, v.z, v.w};
        #pragma unroll
        for (int q = 0; q < 4; ++q) {
            union { uint u; float f; } lo, hi;
            lo.u = u[q] << 16;
            hi.u = u[q] & 0xFFFF0000u;
            s[2 * q]     += lo.f;
            s[2 * q + 1] += hi.f;
        }
    }
    float4* o = (float4*)(out + (size_t)j * 8);
    o[0] = make_float4(s[0], s[1], s[2], s[3]);
    o[1] = make_float4(s[4], s[5], s[6], s[7]);
}

extern "C" void kernel_launch(void* const* d_in, const int* in_sizes, int n_in,
                              void* d_out, int out_size, void* d_ws, size_t ws_size,
                              hipStream_t stream) {
    const float* weight   = (const float*)d_in[0];
    const float* pre_s    = (const float*)d_in[1];
    const float* post_s   = (const float*)d_in[2];
    const float* pre_tr0  = (const float*)d_in[3];
    const float* post_tr0 = (const float*)d_in[4];
    float* out = (float*)d_out;

    uchar* wsb = (uchar*)d_ws;
    uchar* pre_s_t   = wsb + B_PRST;
    uchar* pre_tr_t  = wsb + B_PRTT;
    uchar* post_s_t  = wsb + B_POST;
    uchar* post_tr_t = wsb + B_POTT;
    ushort* Spart    = (ushort*)(wsb + B_END);

    stdp_traces_t<<<dim3(BATCH * (NIN + NOUT) / 64), dim3(256), 0, stream>>>(
        pre_s, post_s, pre_tr0, post_tr0,
        pre_s_t, pre_tr_t, post_s_t, post_tr_t, out);

    stdp_gemm_dual<<<dim3(NIN / 128, NOUT / 128, KS), dim3(256), 0, stream>>>(
        post_s_t, pre_tr_t, post_tr_t, pre_s_t, weight, Spart);

    stdp_finalize<<<dim3((NOUT * NIN / 8) / 128), dim3(128), 0, stream>>>(
        Spart, out);
}

// Round 2
// 98.251 us; speedup vs baseline: 1.0560x; 1.0231x over previous
//
#include <hip/hip_runtime.h>

typedef unsigned short ushort;
typedef unsigned int uint;
typedef unsigned char uchar;
typedef __attribute__((ext_vector_type(8))) int intx8;
typedef __attribute__((ext_vector_type(16))) float floatx16;

// Problem constants
#define T_STEPS 100
#define BATCH   32
#define NIN     1024
#define NOUT    512

// K layout: k = b*SEG + t, t padded 100 -> 112 (KPAD = 3584 = 56 x 64, so the
// MX-scaled 32x32x64 MFMA tiles K exactly with no 128-pad waste).
// Operands stored fp8 e4m3, [rows][K], row stride 3648 B = 57 x 64B
// (64B-aligned rows, 14.25 x 256B rotates L2 channels).
#define SEG      112
#define KPAD     (BATCH * SEG)         // 3584 (GEMM K extent, bytes = elems)
#define KSTRIDEB 3648                  // row stride in bytes
#define KS       8
#define KCHUNK   (KPAD / KS)           // 448 -> 7 K-steps of 64 per block

#define LR_LTP  (1e-4f)
#define LR_LTD  (-1e-4f)
#define INV_B   (1.0f / 32.0f)
#define DECAY   0.951229424500714f     // exp(-1/20)
#define D28     0.246596963941607f     // exp(-28/20)
#define TCH     28                     // t-chunk per thread
#define NCHUNK  4

// Output layout (floats): [delta_w | pre_tr_final | post_tr_final]
#define OFF_PRE  (NOUT * NIN)
#define OFF_POST (OFF_PRE + BATCH * NIN)

// Workspace (bytes): 4 fp8 operands, then bf16 Spart slabs
#define B_PRST  0
#define B_PRTT  ((size_t)NIN * KSTRIDEB)
#define B_POST  ((size_t)2 * NIN * KSTRIDEB)
#define B_POTT  ((size_t)2 * NIN * KSTRIDEB + (size_t)NOUT * KSTRIDEB)
#define B_END   ((size_t)2 * (NIN + NOUT) * KSTRIDEB)   // 11,206,656 B (16-aligned)
// bf16 partial slab stride: NOUT*NIN + 128 ushorts = 1,048,832 B = 4097 x 256B
// (odd 256B multiple -> full L2 channel rotation across slabs)
#define SLABU   (NOUT * NIN + 128)

// NOTE (hard-won, prior session rounds 8+10): no device-scope atomics storms
// and no __threadfence-based cross-block reduction inside the hot kernels —
// both serialized the whole GPU (5-10x regressions). The 3-dispatch structure
// with streamed bf16 partial slabs is the proven optimum here.
//
// NOTE (round 1): kernel B dropped LDS staging + barriers entirely. The
// MX 32x32x64 f8f6f4 fragment is "row = lane&31, 32 contiguous K bytes at
// (lane>>5)*32" — identical to our [row][K] operand layout, so lanes load
// fragments straight from global (L2-resident) and the K-loop has zero
// __syncthreads / vmcnt(0) drains.
//
// NOTE (round 2): KS 16->8 (halves Spart traffic), SEG back to 112 (-12.5%
// operand bytes + MFMA work), grid reordered z-major so linear block id % 8
// == K-slab index -> each XCD owns one K-slab (operands and Spart slab stay
// in that XCD's L2 under round-robin dispatch).

static __device__ __forceinline__ uint pk4_fp8(float a, float b, float c, float d) {
    uint v = 0;
    v = __builtin_amdgcn_cvt_pk_fp8_f32(a, b, v, false);   // low 16 bits
    v = __builtin_amdgcn_cvt_pk_fp8_f32(c, d, v, true);    // high 16 bits
    return v;
}

static __device__ __forceinline__ ushort f2bf(float f) {
    union { float f; unsigned int u; } v; v.f = f;
    unsigned int r = (v.u + 0x7FFFu + ((v.u >> 16) & 1u)) >> 16;   // RNE
    return (ushort)r;
}

// ---------------------------------------------------------------------------
// Kernel A: trace recurrence fused with transpose, fp8 e4m3 outputs.
// Block = 64 chains x 4 t-chunks of 28 (t >= 100: spikes zero-padded).
// Split scan with exp(-28/20) carry fixup. fp8-packed results staged in LDS
// rows of 33 words, then written out cooperatively as 16B chunks.
// (verbatim round-0 version: verified absmax 2^-10)
// ---------------------------------------------------------------------------
__global__ __launch_bounds__(256) void stdp_traces_t(
    const float* __restrict__ pre_s,    // [T,B,NIN]
    const float* __restrict__ post_s,   // [T,B,NOUT]
    const float* __restrict__ pre_tr0,  // [B,NIN]
    const float* __restrict__ post_tr0, // [B,NOUT]
    uchar* __restrict__ pre_s_t, uchar* __restrict__ pre_tr_t,
    uchar* __restrict__ post_s_t, uchar* __restrict__ post_tr_t,
    float* __restrict__ out)
{
    __shared__ uint Ls[64 * 33];   // packed fp8 spikes, 8.25 KB
    __shared__ uint Lt[64 * 33];   // packed fp8 traces
    __shared__ float Eend[NCHUNK][64];

    const int chain = threadIdx.x & 63;
    const int c     = threadIdx.x >> 6;     // t-chunk, wave-uniform
    const int g     = blockIdx.x * 64 + chain;

    const float* src; const float* init;
    int id, stride, outoff;
    if (g < BATCH * NIN) {
        src = pre_s;  init = pre_tr0;
        id = g;               stride = BATCH * NIN;  outoff = OFF_PRE;
    } else {
        src = post_s; init = post_tr0;
        id = g - BATCH * NIN; stride = BATCH * NOUT; outoff = OFF_POST;
    }

    const int t0 = c * TCH;
    float x[TCH];
    #pragma unroll
    for (int m = 0; m < TCH; ++m)
        x[m] = (t0 + m < T_STEPS) ? src[(size_t)(t0 + m) * stride + id] : 0.f;

    // pack spikes to fp8 before the scan overwrites x[]
    uint sp[7];
    #pragma unroll
    for (int j = 0; j < 7; ++j)
        sp[j] = pk4_fp8(x[4*j], x[4*j+1], x[4*j+2], x[4*j+3]);

    // local scan (zero initial condition)
    float e = 0.f;
    #pragma unroll
    for (int m = 0; m < TCH; ++m) { e = e * DECAY + x[m]; x[m] = e; }
    Eend[c][chain] = e;
    __syncthreads();

    // carry into chunk c
    float C = init[id];
    for (int cc = 0; cc < c; ++cc) C = C * D28 + Eend[cc][chain];
    float p = C * DECAY;
    #pragma unroll
    for (int m = 0; m < TCH; ++m) { x[m] += p; p *= DECAY; }

    if (c == NCHUNK - 1) out[outoff + id] = x[15];   // t = 84 + 15 = 99

    // stage packed fp8 into LDS
    #pragma unroll
    for (int j = 0; j < 7; ++j) {
        const uint tj = pk4_fp8(x[4*j], x[4*j+1], x[4*j+2], x[4*j+3]);
        Ls[chain * 33 + c * 7 + j] = sp[j];
        Lt[chain * 33 + c * 7 + j] = tj;
    }
    __syncthreads();

    // cooperative coalesced write-out: 2 ops x 64 rows x 7 16B-chunks = 896
    const int id0 = blockIdx.x * 64;
    uchar *dS, *dT; int b0, ch0;
    if (id0 < BATCH * NIN) {
        b0 = id0 >> 10; ch0 = id0 & 1023; dS = pre_s_t;  dT = pre_tr_t;
    } else {
        const int idq = id0 - BATCH * NIN;
        b0 = idq >> 9;  ch0 = idq & 511;  dS = post_s_t; dT = post_tr_t;
    }
    #pragma unroll
    for (int j = 0; j < 4; ++j) {
        const int q = threadIdx.x + 256 * j;
        if (q < 896) {
            const int op = q >= 448;
            const int qq = q - op * 448;
            const int r  = qq / 7;
            const int cc = qq - r * 7;
            const uint* l = (op ? Lt : Ls) + r * 33 + cc * 4;
            const uint4 v = make_uint4(l[0], l[1], l[2], l[3]);
            uchar* gd = (op ? dT : dS) + (size_t)(ch0 + r) * KSTRIDEB + b0 * SEG + cc * 16;
            *(uint4*)gd = v;
        }
    }
}

// ---------------------------------------------------------------------------
// Kernel B: dual MX-fp8 MFMA GEMM (mfma_scale 32x32x64, scale=1.0), tile
// 128(o) x 64(i), 4 waves 2x2 (each wave 64x32 out), KS=8 K-split
// (512 blocks = 2/CU, 7 K-steps of 64). No LDS, no barriers: fragments
// loaded per-lane direct from global (row = lane&31, 32 contiguous K bytes
// at (lane>>5)*32 — matches storage).
//   P[o,i] = sum_k post_s[k,o]*pre_tr[k,i]
//   D[o,i] = sum_k post_tr[k,o]*pre_s[k,i]
// Epilogue pre-combines with w and stores BF16 partials:
//   Spart[z][o,i] = bf16( c1*(1-w)*P + c2*w*D )
// Grid (KS, 16, 4) z-major-in-x: linear id % 8 == kz -> each XCD owns one
// K-slab; its operand chunk, w working set and Spart slab stay in that L2.
// ---------------------------------------------------------------------------
static __device__ __forceinline__ intx8 ld32(const uchar* p) {
    const uint4 lo = *(const uint4*)p;
    const uint4 hv = *(const uint4*)(p + 16);
    intx8 r;
    r[0] = (int)lo.x; r[1] = (int)lo.y; r[2] = (int)lo.z; r[3] = (int)lo.w;
    r[4] = (int)hv.x; r[5] = (int)hv.y; r[6] = (int)hv.z; r[7] = (int)hv.w;
    return r;
}

__global__ __launch_bounds__(256, 2) void stdp_gemm_dual(
    const uchar* __restrict__ post_s_t, const uchar* __restrict__ pre_tr_t,
    const uchar* __restrict__ post_tr_t, const uchar* __restrict__ pre_s_t,
    const float* __restrict__ wmat, ushort* __restrict__ Spart)
{
    const int kz = blockIdx.x;             // K-slab -> XCD selector
    const int i0 = blockIdx.y * 64;
    const int o0 = blockIdx.z * 128;
    const int k0 = kz * KCHUNK;

    const int tid  = threadIdx.x;
    const int w    = tid >> 6;
    const int lane = tid & 63;
    const int wm   = w & 1;                // o-half (64 rows)
    const int wn   = w >> 1;               // i-half (32 cols)
    const int l32  = lane & 31;
    const int hi   = lane >> 5;

    floatx16 accP[2], accD[2];
    #pragma unroll
    for (int mt = 0; mt < 2; ++mt)
        #pragma unroll
        for (int r = 0; r < 16; ++r) { accP[mt][r] = 0.f; accD[mt][r] = 0.f; }

    const size_t aBase = (size_t)(o0 + wm * 64 + l32) * KSTRIDEB;
    const size_t bBase = (size_t)(i0 + wn * 32 + l32) * KSTRIDEB;

    for (int kb = k0; kb < k0 + KCHUNK; kb += 64) {
        const int ko = kb + (hi << 5);
        intx8 aP[2], aD[2], bP, bD;
        #pragma unroll
        for (int mt = 0; mt < 2; ++mt) {
            const size_t off = aBase + (size_t)(mt * 32) * KSTRIDEB + ko;
            aP[mt] = ld32(post_s_t  + off);
            aD[mt] = ld32(post_tr_t + off);
        }
        {
            const size_t off = bBase + ko;
            bP = ld32(pre_tr_t + off);
            bD = ld32(pre_s_t  + off);
        }
        #pragma unroll
        for (int mt = 0; mt < 2; ++mt) {
            accP[mt] = __builtin_amdgcn_mfma_scale_f32_32x32x64_f8f6f4(
                aP[mt], bP, accP[mt], 0, 0, 0, 127, 0, 127);
            accD[mt] = __builtin_amdgcn_mfma_scale_f32_32x32x64_f8f6f4(
                aD[mt], bD, accD[mt], 0, 0, 0, 127, 0, 127);
        }
    }

    // epilogue: 32x32 C/D layout col = lane&31 (i), row = (r&3)+8*(r>>2)+4*hi (o)
    ushort* Sz = Spart + (size_t)kz * SLABU;
    const float c1 = LR_LTP * INV_B;
    const float c2 = LR_LTD * INV_B;
    #pragma unroll
    for (int mt = 0; mt < 2; ++mt) {
        const int ob = o0 + wm * 64 + mt * 32 + hi * 4;
        const int i  = i0 + wn * 32 + l32;
        #pragma unroll
        for (int r = 0; r < 16; ++r) {
            const int o = ob + (r & 3) + 8 * (r >> 2);
            const size_t idx = (size_t)o * NIN + i;
            const float wv = wmat[idx];
            const float v = c1 * (1.0f - wv) * accP[mt][r]
                          + c2 * wv          * accD[mt][r];
            Sz[idx] = f2bf(v);
        }
    }
}

// ---------------------------------------------------------------------------
// Kernel C: sum the KS bf16 slabs -> fp32 dw. One thread per 8 outputs
// (16B slab loads), fp32 accumulation via bit-unpack.
// 512 blocks x 128 threads (2 blocks/CU) to cover the 8-load latency chains.
// ---------------------------------------------------------------------------
__global__ __launch_bounds__(128) void stdp_finalize(
    const ushort* __restrict__ Spart, float* __restrict__ out)
{
    const int j = blockIdx.x * blockDim.x + threadIdx.x;   // 8-element group
    float s[8] = {0.f, 0.f, 0.f, 0.f, 0.f, 0.f, 0.f, 0.f};
    #pragma unroll
    for (int z = 0; z < KS; ++z) {
        const uint4 v = *(const uint4*)(Spart + (size_t)z * SLABU + (size_t)j * 8);
        const uint u[4] = {v.x, v.y, v.z, v.w};
        #pragma unroll
        for (int q = 0; q < 4; ++q) {
            union { uint u; float f; } lo, hi;
            lo.u = u[q] << 16;
            hi.u = u[q] & 0xFFFF0000u;
            s[2 * q]     += lo.f;
            s[2 * q + 1] += hi.f;
        }
    }
    float4* o = (float4*)(out + (size_t)j * 8);
    o[0] = make_float4(s[0], s[1], s[2], s[3]);
    o[1] = make_float4(s[4], s[5], s[6], s[7]);
}

extern "C" void kernel_launch(void* const* d_in, const int* in_sizes, int n_in,
                              void* d_out, int out_size, void* d_ws, size_t ws_size,
                              hipStream_t stream) {
    const float* weight   = (const float*)d_in[0];
    const float* pre_s    = (const float*)d_in[1];
    const float* post_s   = (const float*)d_in[2];
    const float* pre_tr0  = (const float*)d_in[3];
    const float* post_tr0 = (const float*)d_in[4];
    float* out = (float*)d_out;

    uchar* wsb = (uchar*)d_ws;
    uchar* pre_s_t   = wsb + B_PRST;
    uchar* pre_tr_t  = wsb + B_PRTT;
    uchar* post_s_t  = wsb + B_POST;
    uchar* post_tr_t = wsb + B_POTT;
    ushort* Spart    = (ushort*)(wsb + B_END);

    stdp_traces_t<<<dim3(BATCH * (NIN + NOUT) / 64), dim3(256), 0, stream>>>(
        pre_s, post_s, pre_tr0, post_tr0,
        pre_s_t, pre_tr_t, post_s_t, post_tr_t, out);

    stdp_gemm_dual<<<dim3(KS, NIN / 64, NOUT / 128), dim3(256), 0, stream>>>(
        post_s_t, pre_tr_t, post_tr_t, pre_s_t, weight, Spart);

    stdp_finalize<<<dim3((NOUT * NIN / 8) / 128), dim3(128), 0, stream>>>(
        Spart, out);
}